// Round 4
// baseline (5379.306 us; speedup 1.0000x reference)
//
#include <hip/hip_runtime.h>
#include <hip/hip_bf16.h>
#include <math.h>

#define Nn 10000
#define Ee 160000
#define NPB 64            // dst nodes per block (bucket mean ~65 recs)
#define NBLK 157          // 157 * 64 = 10048 >= 10000
#define NKER 125
#define NBUCK (NBLK * NKER)
#define KCHUNK 16         // k-range per grid.y slice (8 slices)
#define KS ((NKER + KCHUNK - 1) / KCHUNK)

#define MPAD 10048        // 157 * 64
#define NPAD 6912         // 54 * 128
#define NCLS 6890

typedef short bf16x8 __attribute__((ext_vector_type(8)));
typedef float f32x4  __attribute__((ext_vector_type(4)));

// ---------------------------------------------------------------- basis
__global__ __launch_bounds__(256) void basis_kernel(const float* __restrict__ pseudo,
                                                    float* __restrict__ bw,
                                                    int* __restrict__ fl)
{
    int e = blockIdx.x * 256 + threadIdx.x;
    if (e >= Ee) return;
    float p0 = pseudo[e * 3 + 0] * 4.f;
    float p1 = pseudo[e * 3 + 1] * 4.f;
    float p2 = pseudo[e * 3 + 2] * 4.f;
    float f0 = floorf(p0), f1 = floorf(p1), f2 = floorf(p2);
    float fr0 = p0 - f0, fr1 = p1 - f1, fr2 = p2 - f2;
    int lo0 = (int)f0; lo0 = lo0 < 0 ? 0 : (lo0 > 4 ? 4 : lo0);
    int lo1 = (int)f1; lo1 = lo1 < 0 ? 0 : (lo1 > 4 ? 4 : lo1);
    int lo2 = (int)f2; lo2 = lo2 < 0 ? 0 : (lo2 > 4 ? 4 : lo2);
    int hi0 = lo0 + 1 > 4 ? 4 : lo0 + 1;
    int hi1 = lo1 + 1 > 4 ? 4 : lo1 + 1;
    int hi2 = lo2 + 1 > 4 ? 4 : lo2 + 1;
#pragma unroll
    for (int s = 0; s < 8; ++s) {
        int c0 = (s >> 2) & 1, c1 = (s >> 1) & 1, c2 = s & 1;
        float b = (c0 ? fr0 : 1.f - fr0) * (c1 ? fr1 : 1.f - fr1) * (c2 ? fr2 : 1.f - fr2);
        int f = (c0 ? hi0 : lo0) + 5 * (c1 ? hi1 : lo1) + 25 * (c2 ? hi2 : lo2);
        bw[e * 8 + s] = b;
        fl[e * 8 + s] = f;
    }
}

// ---------------------------------------------------------------- degree
__global__ __launch_bounds__(256) void deg_kernel(const int* __restrict__ dst, int* __restrict__ degi)
{
    int e = blockIdx.x * 256 + threadIdx.x;
    if (e >= Ee) return;
    atomicAdd(&degi[dst[e]], 1);
}

__global__ __launch_bounds__(256) void invdeg_kernel(const int* __restrict__ degi, float* __restrict__ invdeg)
{
    int n = blockIdx.x * 256 + threadIdx.x;
    if (n >= Nn) return;
    int d = degi[n];
    invdeg[n] = 1.f / (float)(d > 0 ? d : 1);
}

// ---------------------------------------------------------------- pair sort (counting sort by (dstblock, k))
__global__ __launch_bounds__(256) void hist_kernel(const int* __restrict__ dst, const int* __restrict__ fl,
                                                   int* __restrict__ hist)
{
    int t = blockIdx.x * 256 + threadIdx.x;
    if (t >= Ee * 8) return;
    int e = t >> 3;
    int key = (dst[e] >> 6) * NKER + fl[t];
    atomicAdd(&hist[key], 1);
}

__global__ __launch_bounds__(1024) void scan_kernel(const int* __restrict__ hist, int* __restrict__ boff)
{
    const int T = 1024;
    const int per = (NBUCK + T - 1) / T;
    int t = threadIdx.x;
    int beg = t * per;
    int end = beg + per; if (end > NBUCK) end = NBUCK;
    int s = 0;
    for (int i = beg; i < end && i < NBUCK; ++i) s += hist[i];
    __shared__ int tmp[1024];
    tmp[t] = s;
    __syncthreads();
    for (int o2 = 1; o2 < 1024; o2 <<= 1) {
        int v = (t >= o2) ? tmp[t - o2] : 0;
        __syncthreads();
        tmp[t] += v;
        __syncthreads();
    }
    int run = tmp[t] - s;   // exclusive prefix for this thread's range
    for (int i = beg; i < end && i < NBUCK; ++i) { boff[i] = run; run += hist[i]; }
    if (t == T - 1) boff[NBUCK] = run;
}

__global__ __launch_bounds__(256) void fill_kernel(const int* __restrict__ srcA, const int* __restrict__ dstA,
                                                   const float* __restrict__ bw, const int* __restrict__ fl,
                                                   int* __restrict__ cursor, uint2* __restrict__ recs)
{
    int t = blockIdx.x * 256 + threadIdx.x;
    if (t >= Ee * 8) return;
    int e = t >> 3;
    int d = dstA[e];
    int key = (d >> 6) * NKER + fl[t];
    int pos = atomicAdd(&cursor[key], 1);
    unsigned meta = (unsigned)srcA[e] | ((unsigned)(d & 63) << 16);
    recs[pos] = make_uint2(meta, __float_as_uint(bw[t]));
}

// ---------------------------------------------------------------- spline conv core
// Wave = bucket (dstblock, k); lane = output channel o (R0 layout: W column
// resident in per-lane regs, loaded ONCE per bucket). The per-record x-row
// broadcast -- R0's serial s_load chain (~900 cyc/rec) and R2's per-record W
// re-stream -- is replaced by LDS staging: per batch of B records, lanes
// gather x rows (per-lane f32x4, wt folded in => free zero-padding), ds_write
// to a padded slab, issue next batch's gathers, then compute: per record
// 16 uniform-address ds_read_b128 (broadcast, conflict-free) + 64 fmac +
// 1 LDS atomic. No scalar traffic, no serial chain.
template <int CIN, int COUT, int B>
__global__ __launch_bounds__(256, 3) void conv_pairs_kernel(const uint2* __restrict__ recs,
                                                            const int* __restrict__ boff,
                                                            const float* __restrict__ xin,
                                                            const float* __restrict__ W,
                                                            float* __restrict__ agg)
{
    constexpr int RSTR = (CIN >= 4) ? CIN + 4 : 2;       // padded row stride (floats)
    constexpr int LPR  = 64 / B;                          // gather lanes per row
    constexpr int QC   = (CIN >= 4) ? (CIN / 4 / LPR) : 1;  // f32x4 chunks per gather lane

    __shared__ float aggl[NPB * COUT];
    __shared__ __align__(16) float xs_lds[4][B * RSTR];
    __shared__ int dlb[4][(CIN >= 4) ? B : 1];

    const int blk = blockIdx.x;
    for (int idx = threadIdx.x; idx < NPB * COUT; idx += 256) aggl[idx] = 0.f;
    __syncthreads();

    const int lane = threadIdx.x & 63;
    const int wid  = threadIdx.x >> 6;
    const int o    = lane;

    int k0 = blockIdx.y * KCHUNK;
    int k1 = k0 + KCHUNK; if (k1 > NKER) k1 = NKER;

    const int grow = lane & (B - 1);      // gather: row owned by this lane
    const int gcb  = lane / B;            // gather: chunk-base within row

    for (int k = k0 + wid; k < k1; k += 4) {
        const int kk = __builtin_amdgcn_readfirstlane(k);
        const int bidx = blk * NKER + kk;
        const int pb = boff[bidx], pe = boff[bidx + 1];
        if (pb >= pe) continue;

        // W[k] column o, resident in per-lane regs for the whole bucket
        const float* __restrict__ Wk = W + (size_t)kk * CIN * COUT;
        float wreg[CIN];
#pragma unroll
        for (int i = 0; i < CIN; ++i)
            wreg[i] = (o < COUT) ? Wk[i * COUT + o] : 0.f;

        const int cnt = pe - pb;
        const int nb = (cnt + B - 1) / B;

        // gather state (batch in flight)
        f32x4 gx[QC];
        float gx1 = 0.f;
        float gwt = 0.f;
        int   gdls = 0;

        auto GATHER = [&](int b) {
            int rid0 = pb + b * B + grow;
            bool v = rid0 < pe;
            uint2 rr = recs[v ? rid0 : (pe - 1)];
            gwt = v ? __uint_as_float(rr.y) : 0.f;
            int src = (int)(rr.x & 0xFFFFu);
            gdls = (int)(rr.x >> 16) * COUT;
            if constexpr (CIN >= 4) {
                const f32x4* __restrict__ xr = (const f32x4*)(xin + (size_t)src * CIN);
#pragma unroll
                for (int q = 0; q < QC; ++q) gx[q] = xr[gcb * QC + q];
            } else {
                gx1 = xin[src];
            }
        };

        auto STAGE = [&]() {
            if constexpr (CIN >= 4) {
                f32x4* __restrict__ xw = (f32x4*)&xs_lds[wid][grow * RSTR + gcb * QC * 4];
#pragma unroll
                for (int q = 0; q < QC; ++q) {
                    f32x4 sv;
                    sv[0] = gx[q][0] * gwt; sv[1] = gx[q][1] * gwt;
                    sv[2] = gx[q][2] * gwt; sv[3] = gx[q][3] * gwt;
                    xw[q] = sv;
                }
                if (gcb == 0) dlb[wid][grow] = gdls;
            } else {
                uint2* __restrict__ xw = (uint2*)&xs_lds[wid][0];
                xw[grow] = make_uint2(__float_as_uint(gx1 * gwt), (unsigned)gdls);
            }
        };

        GATHER(0);
        for (int b = 0; b < nb; ++b) {
            STAGE();                       // waits vmcnt for batch b's gathers
            if (b + 1 < nb) GATHER(b + 1); // issue next batch's loads now
            // compute batch b from LDS (uniform-address broadcast reads)
            if constexpr (CIN >= 4) {
#pragma unroll 2
                for (int r = 0; r < B; ++r) {
                    const f32x4* __restrict__ xv = (const f32x4*)&xs_lds[wid][r * RSTR];
                    float m0 = 0.f, m1 = 0.f, m2 = 0.f, m3 = 0.f;
#pragma unroll
                    for (int c = 0; c < CIN / 4; ++c) {
                        f32x4 x4 = xv[c];
                        m0 = fmaf(x4[0], wreg[4 * c + 0], m0);
                        m1 = fmaf(x4[1], wreg[4 * c + 1], m1);
                        m2 = fmaf(x4[2], wreg[4 * c + 2], m2);
                        m3 = fmaf(x4[3], wreg[4 * c + 3], m3);
                    }
                    float m = (m0 + m1) + (m2 + m3);
                    int doff = dlb[wid][r];
                    if (o < COUT) atomicAdd(&aggl[doff + o], m);
                }
            } else {
#pragma unroll 4
                for (int r = 0; r < B; ++r) {
                    uint2 q = ((const uint2*)&xs_lds[wid][0])[r];
                    float m = __uint_as_float(q.x) * wreg[0];
                    if (o < COUT) atomicAdd(&aggl[(int)q.y + o], m);
                }
            }
        }
    }
    __syncthreads();
    for (int idx = threadIdx.x; idx < NPB * COUT; idx += 256) {
        int n = blk * NPB + idx / COUT;
        if (n < Nn) atomicAdd(&agg[n * COUT + (idx % COUT)], aggl[idx]);
    }
}

// ---------------------------------------------------------------- conv epilogue: /deg + root + bias + elu
template <int CIN, int COUT>
__global__ __launch_bounds__(256) void epilogue_kernel(const float* __restrict__ agg,
                                                       const float* __restrict__ xin,
                                                       const float* __restrict__ root,
                                                       const float* __restrict__ bias,
                                                       const float* __restrict__ invdeg,
                                                       float* __restrict__ out)
{
    int idx = blockIdx.x * 256 + threadIdx.x;
    int n = idx / COUT, o = idx % COUT;
    if (n >= Nn) return;
    float r0 = 0.f, r1 = 0.f;
#pragma unroll
    for (int i = 0; i < CIN; i += 2) {
        r0 += xin[n * CIN + i] * root[i * COUT + o];
        if (CIN > 1) r1 += xin[n * CIN + i + 1] * root[(i + 1) * COUT + o];
    }
    float v = agg[n * COUT + o] * invdeg[n] + r0 + r1 + bias[o];
    out[n * COUT + o] = v > 0.f ? v : expm1f(v);
}

// ---------------------------------------------------------------- lin1: 64 -> 256, elu, emit bf16
__global__ __launch_bounds__(256) void lin1_kernel(const float* __restrict__ h,
                                                   const float* __restrict__ w1,
                                                   const float* __restrict__ b1,
                                                   __hip_bfloat16* __restrict__ out)
{
    int n = blockIdx.x;
    __shared__ float hl[64];
    if (threadIdx.x < 64) hl[threadIdx.x] = h[n * 64 + threadIdx.x];
    __syncthreads();
    int j = threadIdx.x;
    float a0 = b1[j], a1 = 0.f, a2 = 0.f, a3 = 0.f;
#pragma unroll
    for (int i = 0; i < 64; i += 4) {
        a0 += hl[i + 0] * w1[(i + 0) * 256 + j];
        a1 += hl[i + 1] * w1[(i + 1) * 256 + j];
        a2 += hl[i + 2] * w1[(i + 2) * 256 + j];
        a3 += hl[i + 3] * w1[(i + 3) * 256 + j];
    }
    float acc = (a0 + a1) + (a2 + a3);
    float v = acc > 0.f ? acc : expm1f(acc);
    out[(size_t)n * 256 + j] = __float2bfloat16(v);
}

// ---------------------------------------------------------------- w2 transpose + bf16 convert
__global__ __launch_bounds__(256) void w2t_kernel(const float* __restrict__ w2,
                                                  __hip_bfloat16* __restrict__ w2t)
{
    __shared__ float t[32][33];
    int n0 = blockIdx.x * 32;       // class dim tile
    int k0 = blockIdx.y * 32;       // feature dim tile
    int tx = threadIdx.x & 31, ty = threadIdx.x >> 5;   // ty: 0..7
#pragma unroll
    for (int q = 0; q < 4; ++q) {
        int k = k0 + ty + 8 * q, n = n0 + tx;
        t[ty + 8 * q][tx] = (n < NCLS) ? w2[(size_t)k * NCLS + n] : 0.f;
    }
    __syncthreads();
#pragma unroll
    for (int q = 0; q < 4; ++q) {
        int n = n0 + ty + 8 * q;
        w2t[(size_t)n * 256 + k0 + tx] = __float2bfloat16(t[tx][ty + 8 * q]);
    }
}

// ---------------------------------------------------------------- lin2 via MFMA
__global__ __launch_bounds__(256) void lin2_mfma_kernel(const __hip_bfloat16* __restrict__ hbf,
                                                        const __hip_bfloat16* __restrict__ w2t,
                                                        const float* __restrict__ b2,
                                                        float* __restrict__ out)
{
    const int tid  = threadIdx.x;
    const int lane = tid & 63, wid = tid >> 6;
    const int wr = wid & 1, wc = wid >> 1;
    const int quad = lane >> 4, lq = lane & 15;

    const int mbase = blockIdx.x * 64 + wr * 32;
    const int nbase = blockIdx.y * 128 + wc * 64;

    f32x4 acc[2][4];
#pragma unroll
    for (int i = 0; i < 2; ++i)
#pragma unroll
        for (int j = 0; j < 4; ++j) acc[i][j] = (f32x4){0.f, 0.f, 0.f, 0.f};

    const unsigned short* A = (const unsigned short*)hbf;
    const unsigned short* B = (const unsigned short*)w2t;

    for (int kc = 0; kc < 256; kc += 32) {
        bf16x8 af[2], bfr[4];
#pragma unroll
        for (int mt = 0; mt < 2; ++mt)
            af[mt] = *(const bf16x8*)(A + (size_t)(mbase + mt * 16 + lq) * 256 + kc + quad * 8);
#pragma unroll
        for (int nt = 0; nt < 4; ++nt)
            bfr[nt] = *(const bf16x8*)(B + (size_t)(nbase + nt * 16 + lq) * 256 + kc + quad * 8);
#pragma unroll
        for (int mt = 0; mt < 2; ++mt)
#pragma unroll
            for (int nt = 0; nt < 4; ++nt)
                acc[mt][nt] = __builtin_amdgcn_mfma_f32_16x16x32_bf16(af[mt], bfr[nt], acc[mt][nt], 0, 0, 0);
    }

#pragma unroll
    for (int nt = 0; nt < 4; ++nt) {
        int col = nbase + nt * 16 + lq;
        if (col >= NCLS) continue;
        float bb = b2[col];
#pragma unroll
        for (int mt = 0; mt < 2; ++mt) {
#pragma unroll
            for (int r = 0; r < 4; ++r) {
                int row = mbase + mt * 16 + quad * 4 + r;
                if (row < Nn) out[(size_t)row * NCLS + col] = acc[mt][nt][r] + bb;
            }
        }
    }
}

// ---------------------------------------------------------------- log_softmax (in place)
__global__ __launch_bounds__(1024) void lsm_kernel(float* __restrict__ out)
{
    int row = blockIdx.x;
    float* p = out + (size_t)row * NCLS;
    __shared__ float red[16];
    int tid = threadIdx.x, lane = tid & 63, wid = tid >> 6;

    float m = -3.4e38f;
    for (int jj = tid; jj < NCLS; jj += 1024) m = fmaxf(m, p[jj]);
#pragma unroll
    for (int off = 32; off > 0; off >>= 1) m = fmaxf(m, __shfl_down(m, off));
    if (lane == 0) red[wid] = m;
    __syncthreads();
    if (tid == 0) {
        float mm = red[0];
        for (int w = 1; w < 16; ++w) mm = fmaxf(mm, red[w]);
        red[0] = mm;
    }
    __syncthreads();
    m = red[0];
    __syncthreads();

    float s = 0.f;
    for (int jj = tid; jj < NCLS; jj += 1024) s += expf(p[jj] - m);
#pragma unroll
    for (int off = 32; off > 0; off >>= 1) s += __shfl_down(s, off);
    if (lane == 0) red[wid] = s;
    __syncthreads();
    if (tid == 0) {
        float ss = 0.f;
        for (int w = 1; w < 16; ++w) ss += red[w];
        red[0] += ss;
    }
    __syncthreads();
    float lse = m + logf(red[0]);
    for (int jj = tid; jj < NCLS; jj += 1024) p[jj] -= lse;
}

// ---------------------------------------------------------------- launch
extern "C" void kernel_launch(void* const* d_in, const int* in_sizes, int n_in,
                              void* d_out, int out_size, void* d_ws, size_t ws_size,
                              hipStream_t stream)
{
    const float* x      = (const float*)d_in[0];
    const int*   ei     = (const int*)d_in[1];
    const float* pseudo = (const float*)d_in[2];
    const float* W1     = (const float*)d_in[3];
    const float* root1  = (const float*)d_in[4];
    const float* b1     = (const float*)d_in[5];
    const float* W2     = (const float*)d_in[6];
    const float* root2  = (const float*)d_in[7];
    const float* b2     = (const float*)d_in[8];
    const float* Ws     = (const float*)d_in[9];
    const float* roots  = (const float*)d_in[10];
    const float* bs     = (const float*)d_in[11];
    const float* l1w    = (const float*)d_in[12];
    const float* l1b    = (const float*)d_in[13];
    const float* l2w    = (const float*)d_in[14];
    const float* l2b    = (const float*)d_in[15];
    float* out = (float*)d_out;

    const int* srcA = ei;
    const int* dstA = ei + Ee;

    char* base = (char*)d_ws;
    size_t off = 0;
    auto carve = [&](size_t bytes) -> void* {
        void* p = base + off;
        off += (bytes + 255) & ~(size_t)255;
        return p;
    };
    float* bw     = (float*)carve((size_t)Ee * 8 * 4);
    int*   fl     = (int*)carve((size_t)Ee * 8 * 4);
    int*   hist   = (int*)carve((size_t)NBUCK * 4);
    int*   boff   = (int*)carve((size_t)(NBUCK + 1) * 4);
    int*   cursor = (int*)carve((size_t)NBUCK * 4);
    uint2* recs   = (uint2*)carve((size_t)Ee * 8 * 8);
    int*   degi   = (int*)carve((size_t)Nn * 4);
    float* invdeg = (float*)carve((size_t)Nn * 4);
    float* agg    = (float*)carve((size_t)Nn * 64 * 4);
    float* hA     = (float*)carve((size_t)Nn * 64 * 4);
    float* hB     = (float*)carve((size_t)Nn * 64 * 4);
    __hip_bfloat16* hbf = (__hip_bfloat16*)carve((size_t)MPAD * 256 * 2);
    __hip_bfloat16* w2t = (__hip_bfloat16*)carve((size_t)NPAD * 256 * 2);
    (void)ws_size; (void)n_in; (void)in_sizes; (void)out_size;

    hipMemsetAsync(hist, 0, (size_t)NBUCK * 4, stream);
    hipMemsetAsync(degi, 0, (size_t)Nn * 4, stream);
    hipMemsetAsync(hbf, 0, (size_t)MPAD * 256 * 2, stream);   // zero-pad rows >= Nn

    basis_kernel<<<(Ee + 255) / 256, 256, 0, stream>>>(pseudo, bw, fl);
    deg_kernel<<<(Ee + 255) / 256, 256, 0, stream>>>(dstA, degi);
    invdeg_kernel<<<(Nn + 255) / 256, 256, 0, stream>>>(degi, invdeg);
    hist_kernel<<<(Ee * 8 + 255) / 256, 256, 0, stream>>>(dstA, fl, hist);
    scan_kernel<<<1, 1024, 0, stream>>>(hist, boff);
    hipMemcpyAsync(cursor, boff, (size_t)NBUCK * 4, hipMemcpyDeviceToDevice, stream);
    fill_kernel<<<(Ee * 8 + 255) / 256, 256, 0, stream>>>(srcA, dstA, bw, fl, cursor, recs);
    w2t_kernel<<<dim3((NPAD + 31) / 32, 8), 256, 0, stream>>>(l2w, w2t);

    const dim3 cgrid(NBLK, KS);

    // layer 1: 1 -> 32
    hipMemsetAsync(agg, 0, (size_t)Nn * 64 * 4, stream);
    conv_pairs_kernel<1, 32, 64><<<cgrid, 256, 0, stream>>>(recs, boff, x, W1, agg);
    epilogue_kernel<1, 32><<<(Nn * 32 + 255) / 256, 256, 0, stream>>>(agg, x, root1, b1, invdeg, hA);

    // layer 2: 32 -> 64
    hipMemsetAsync(agg, 0, (size_t)Nn * 64 * 4, stream);
    conv_pairs_kernel<32, 64, 32><<<cgrid, 256, 0, stream>>>(recs, boff, hA, W2, agg);
    epilogue_kernel<32, 64><<<(Nn * 64 + 255) / 256, 256, 0, stream>>>(agg, hA, root2, b2, invdeg, hB);

    // layers 3..6: 64 -> 64
    float* cin = hB;
    float* cot = hA;
    for (int l = 0; l < 4; ++l) {
        hipMemsetAsync(agg, 0, (size_t)Nn * 64 * 4, stream);
        conv_pairs_kernel<64, 64, 16><<<cgrid, 256, 0, stream>>>(recs, boff, cin, Ws + (size_t)l * 125 * 64 * 64, agg);
        epilogue_kernel<64, 64><<<(Nn * 64 + 255) / 256, 256, 0, stream>>>(
            agg, cin, roots + (size_t)l * 64 * 64, bs + (size_t)l * 64, invdeg, cot);
        float* t = cin; cin = cot; cot = t;
    }

    lin1_kernel<<<Nn, 256, 0, stream>>>(cin, l1w, l1b, hbf);
    lin2_mfma_kernel<<<dim3(MPAD / 64, NPAD / 128), 256, 0, stream>>>(hbf, w2t, l2b, out);
    lsm_kernel<<<Nn, 1024, 0, stream>>>(out);
}

// Round 5
// 4132.655 us; speedup vs baseline: 1.3017x; 1.3017x over previous
//
#include <hip/hip_runtime.h>
#include <hip/hip_bf16.h>
#include <hip/hip_fp16.h>
#include <math.h>

#define Nn 10000
#define Ee 160000
#define NPB 64            // dst nodes per block
#define NBLK 157          // 157 * 64 = 10048 >= 10000
#define NKER 125
#define NBUCK (NBLK * NKER)
#define KCHUNK 16         // k-range per grid.y slice (8 slices)
#define KS ((NKER + KCHUNK - 1) / KCHUNK)

#define MPAD 10048        // 157 * 64
#define NPAD 6912         // 54 * 128
#define NCLS 6890

typedef float    f32x4 __attribute__((ext_vector_type(4)));
typedef _Float16 f16x8 __attribute__((ext_vector_type(8)));

// ---------------------------------------------------------------- basis
__global__ __launch_bounds__(256) void basis_kernel(const float* __restrict__ pseudo,
                                                    float* __restrict__ bw,
                                                    int* __restrict__ fl)
{
    int e = blockIdx.x * 256 + threadIdx.x;
    if (e >= Ee) return;
    float p0 = pseudo[e * 3 + 0] * 4.f;
    float p1 = pseudo[e * 3 + 1] * 4.f;
    float p2 = pseudo[e * 3 + 2] * 4.f;
    float f0 = floorf(p0), f1 = floorf(p1), f2 = floorf(p2);
    float fr0 = p0 - f0, fr1 = p1 - f1, fr2 = p2 - f2;
    int lo0 = (int)f0; lo0 = lo0 < 0 ? 0 : (lo0 > 4 ? 4 : lo0);
    int lo1 = (int)f1; lo1 = lo1 < 0 ? 0 : (lo1 > 4 ? 4 : lo1);
    int lo2 = (int)f2; lo2 = lo2 < 0 ? 0 : (lo2 > 4 ? 4 : lo2);
    int hi0 = lo0 + 1 > 4 ? 4 : lo0 + 1;
    int hi1 = lo1 + 1 > 4 ? 4 : lo1 + 1;
    int hi2 = lo2 + 1 > 4 ? 4 : lo2 + 1;
#pragma unroll
    for (int s = 0; s < 8; ++s) {
        int c0 = (s >> 2) & 1, c1 = (s >> 1) & 1, c2 = s & 1;
        float b = (c0 ? fr0 : 1.f - fr0) * (c1 ? fr1 : 1.f - fr1) * (c2 ? fr2 : 1.f - fr2);
        int f = (c0 ? hi0 : lo0) + 5 * (c1 ? hi1 : lo1) + 25 * (c2 ? hi2 : lo2);
        bw[e * 8 + s] = b;
        fl[e * 8 + s] = f;
    }
}

// ---------------------------------------------------------------- degree
__global__ __launch_bounds__(256) void deg_kernel(const int* __restrict__ dst, int* __restrict__ degi)
{
    int e = blockIdx.x * 256 + threadIdx.x;
    if (e >= Ee) return;
    atomicAdd(&degi[dst[e]], 1);
}

__global__ __launch_bounds__(256) void invdeg_kernel(const int* __restrict__ degi, float* __restrict__ invdeg)
{
    int n = blockIdx.x * 256 + threadIdx.x;
    if (n >= Nn) return;
    int d = degi[n];
    invdeg[n] = 1.f / (float)(d > 0 ? d : 1);
}

// ---------------------------------------------------------------- pair sort (counting sort by (dstblock, k))
__global__ __launch_bounds__(256) void hist_kernel(const int* __restrict__ dst, const int* __restrict__ fl,
                                                   int* __restrict__ hist)
{
    int t = blockIdx.x * 256 + threadIdx.x;
    if (t >= Ee * 8) return;
    int e = t >> 3;
    int key = (dst[e] >> 6) * NKER + fl[t];
    atomicAdd(&hist[key], 1);
}

__global__ __launch_bounds__(1024) void scan_kernel(const int* __restrict__ hist, int* __restrict__ boff)
{
    const int T = 1024;
    const int per = (NBUCK + T - 1) / T;
    int t = threadIdx.x;
    int beg = t * per;
    int end = beg + per; if (end > NBUCK) end = NBUCK;
    int s = 0;
    for (int i = beg; i < end && i < NBUCK; ++i) s += hist[i];
    __shared__ int tmp[1024];
    tmp[t] = s;
    __syncthreads();
    for (int o2 = 1; o2 < 1024; o2 <<= 1) {
        int v = (t >= o2) ? tmp[t - o2] : 0;
        __syncthreads();
        tmp[t] += v;
        __syncthreads();
    }
    int run = tmp[t] - s;   // exclusive prefix for this thread's range
    for (int i = beg; i < end && i < NBUCK; ++i) { boff[i] = run; run += hist[i]; }
    if (t == T - 1) boff[NBUCK] = run;
}

__global__ __launch_bounds__(256) void fill_kernel(const int* __restrict__ srcA, const int* __restrict__ dstA,
                                                   const float* __restrict__ bw, const int* __restrict__ fl,
                                                   int* __restrict__ cursor, uint2* __restrict__ recs)
{
    int t = blockIdx.x * 256 + threadIdx.x;
    if (t >= Ee * 8) return;
    int e = t >> 3;
    int d = dstA[e];
    int key = (d >> 6) * NKER + fl[t];
    int pos = atomicAdd(&cursor[key], 1);
    unsigned meta = (unsigned)srcA[e] | ((unsigned)(d & 63) << 16);
    recs[pos] = make_uint2(meta, __float_as_uint(bw[t]));
}

// ---------------------------------------------------------------- W pre-transpose to f16 MFMA B-fragment layout
// WB[k][nt][kc][lane][8]: lane (lq=col,quad) holds W[kc*32+quad*8+j][nt*16+lq]
template <int CIN>
__global__ __launch_bounds__(256) void wb_kernel(const float* __restrict__ W, _Float16* __restrict__ WB)
{
    constexpr int NKC = CIN / 32;
    int t = blockIdx.x * 256 + threadIdx.x;
    int total = NKER * 4 * NKC * 512;
    if (t >= total) return;
    int j = t & 7;
    int lane = (t >> 3) & 63;
    int rem = t >> 9;
    int kc = rem % NKC; rem /= NKC;
    int nt = rem & 3; rem >>= 2;
    int k = rem;
    int ki = kc * 32 + (lane >> 4) * 8 + j;
    int o  = nt * 16 + (lane & 15);
    WB[t] = (_Float16)W[((size_t)k * CIN + ki) * 64 + o];
}

// ---------------------------------------------------------------- spline conv via MFMA (CIN in {32,64}, COUT=64)
// Wave = bucket (dstblock, k). Per batch of 16 records: stage wt-scaled f16
// x-rows into LDS (per-lane vector gathers, next batch issued before compute),
// A-frags = 2 non-uniform ds_read_b128 (full LDS BW), B = W[k] frags loaded
// once per bucket from pre-transposed blob, 8 (or 4) MFMA, 16 ds_add_f32
// row-scatter into aggl. Replaces R4's 16 broadcast ds_reads/record (LDS-pipe
// bound, 19% VALUBusy) with ~13 LDS slots/record + MFMA.
template <int CIN>
__global__ __launch_bounds__(256, 3) void conv_mfma_kernel(const uint2* __restrict__ recs,
                                                           const int* __restrict__ boff,
                                                           const float* __restrict__ xin,
                                                           const _Float16* __restrict__ WB,
                                                           float* __restrict__ agg)
{
    constexpr int NKC = CIN / 32;          // K chunks of 32
    constexpr int RH  = CIN + 8;           // staged row stride in halves (16B multiple)
    constexpr int STR = 65;                // aggl row stride (floats)
    constexpr int QG  = CIN / 16;          // f32x4 chunks gathered per lane

    __shared__ float aggl[NPB * STR];
    __shared__ __align__(16) _Float16 xh[4][16 * RH];
    __shared__ __align__(16) int dlb[4][16];

    const int blk = blockIdx.x;
    for (int idx = threadIdx.x; idx < NPB * STR; idx += 256) aggl[idx] = 0.f;
    __syncthreads();

    const int lane = threadIdx.x & 63;
    const int wid  = threadIdx.x >> 6;
    const int lq   = lane & 15;
    const int quad = lane >> 4;

    int k0 = blockIdx.y * KCHUNK;
    int k1 = k0 + KCHUNK; if (k1 > NKER) k1 = NKER;

    for (int k = k0 + wid; k < k1; k += 4) {
        const int kk = __builtin_amdgcn_readfirstlane(k);
        const int bidx = blk * NKER + kk;
        const int pb = boff[bidx], pe = boff[bidx + 1];
        if (pb >= pe) continue;

        // B fragments for W[kk], once per bucket (16B/lane coalesced loads)
        f16x8 bfr[4][NKC];
        {
            const _Float16* __restrict__ wbk = WB + (size_t)kk * (4 * NKC * 512);
#pragma unroll
            for (int nt = 0; nt < 4; ++nt)
#pragma unroll
                for (int kc = 0; kc < NKC; ++kc)
                    bfr[nt][kc] = *(const f16x8*)(wbk + (size_t)((nt * NKC + kc) * 64 + lane) * 8);
        }

        const int nb = (pe - pb + 15) >> 4;

        f32x4 gx[QG];
        float gwt = 0.f;
        int   gdl = 0;

        auto GATHER = [&](int b) {
            int rid = pb + b * 16 + lq;
            bool v = rid < pe;
            uint2 rr = recs[v ? rid : (pe - 1)];
            gwt = v ? __uint_as_float(rr.y) : 0.f;
            int src = (int)(rr.x & 0xFFFFu);
            gdl = (int)(rr.x >> 16);
            const f32x4* __restrict__ xr = (const f32x4*)(xin + (size_t)src * CIN);
#pragma unroll
            for (int q = 0; q < QG; ++q) gx[q] = xr[quad * QG + q];
        };

        auto STAGE = [&]() {
            _Float16* __restrict__ xw = &xh[wid][lq * RH + quad * (4 * QG)];
#pragma unroll
            for (int h8 = 0; h8 < QG / 2; ++h8) {
                f16x8 hv;
#pragma unroll
                for (int j = 0; j < 4; ++j) {
                    hv[j]     = (_Float16)(gx[2 * h8][j]     * gwt);
                    hv[4 + j] = (_Float16)(gx[2 * h8 + 1][j] * gwt);
                }
                *(f16x8*)(xw + h8 * 8) = hv;
            }
            if (quad == 0) dlb[wid][lq] = gdl;
        };

        GATHER(0);
        for (int b = 0; b < nb; ++b) {
            STAGE();                        // waits vmcnt for batch b
            if (b + 1 < nb) GATHER(b + 1);  // overlap next gathers with compute

            f16x8 af[NKC];
#pragma unroll
            for (int kc = 0; kc < NKC; ++kc)
                af[kc] = *(const f16x8*)&xh[wid][lq * RH + kc * 32 + quad * 8];

            int4 dlv = *(const int4*)&dlb[wid][quad * 4];
            const int dls[4] = {dlv.x, dlv.y, dlv.z, dlv.w};

            f32x4 acc[4];
#pragma unroll
            for (int nt = 0; nt < 4; ++nt) {
                acc[nt] = (f32x4){0.f, 0.f, 0.f, 0.f};
#pragma unroll
                for (int kc = 0; kc < NKC; ++kc)
                    acc[nt] = __builtin_amdgcn_mfma_f32_16x16x32_f16(af[kc], bfr[nt][kc], acc[nt], 0, 0, 0);
            }

#pragma unroll
            for (int nt = 0; nt < 4; ++nt)
#pragma unroll
                for (int r = 0; r < 4; ++r)
                    atomicAdd(&aggl[dls[r] * STR + nt * 16 + lq], acc[nt][r]);
        }
    }
    __syncthreads();
    for (int idx = threadIdx.x; idx < NPB * 64; idx += 256) {
        int n = blk * NPB + (idx >> 6);
        if (n < Nn) atomicAdd(&agg[n * 64 + (idx & 63)], aggl[(idx >> 6) * STR + (idx & 63)]);
    }
}

// ---------------------------------------------------------------- layer-1 conv (CIN=1, COUT=32): lane = record
__global__ __launch_bounds__(256, 3) void conv1_kernel(const uint2* __restrict__ recs,
                                                       const int* __restrict__ boff,
                                                       const float* __restrict__ xin,
                                                       const float* __restrict__ W,
                                                       float* __restrict__ agg)
{
    constexpr int STR = 33;
    __shared__ float aggl[NPB * STR];
    const int blk = blockIdx.x;
    for (int idx = threadIdx.x; idx < NPB * STR; idx += 256) aggl[idx] = 0.f;
    __syncthreads();

    const int lane = threadIdx.x & 63;
    const int wid  = threadIdx.x >> 6;
    int k0 = blockIdx.y * KCHUNK;
    int k1 = k0 + KCHUNK; if (k1 > NKER) k1 = NKER;

    for (int k = k0 + wid; k < k1; k += 4) {
        const int kk = __builtin_amdgcn_readfirstlane(k);
        const int bidx = blk * NKER + kk;
        const int pb = boff[bidx], pe = boff[bidx + 1];
        if (pb >= pe) continue;
        const float* __restrict__ Wk = W + kk * 32;
        float w[32];
#pragma unroll
        for (int o = 0; o < 32; ++o) w[o] = Wk[o];   // wave-uniform -> SGPRs, once per bucket

        for (int p = pb; p < pe; p += 64) {
            int j = p + lane;
            bool v = j < pe;
            uint2 rr = recs[v ? j : (pe - 1)];
            float wt = v ? __uint_as_float(rr.y) : 0.f;
            float xv = xin[rr.x & 0xFFFFu] * wt;
            int dbase = (int)(rr.x >> 16) * STR;
#pragma unroll
            for (int o = 0; o < 32; ++o)
                atomicAdd(&aggl[dbase + o], xv * w[o]);
        }
    }
    __syncthreads();
    for (int idx = threadIdx.x; idx < NPB * 32; idx += 256) {
        int n = blk * NPB + (idx >> 5);
        if (n < Nn) atomicAdd(&agg[n * 32 + (idx & 31)], aggl[(idx >> 5) * STR + (idx & 31)]);
    }
}

// ---------------------------------------------------------------- conv epilogue: /deg + root + bias + elu
template <int CIN, int COUT>
__global__ __launch_bounds__(256) void epilogue_kernel(const float* __restrict__ agg,
                                                       const float* __restrict__ xin,
                                                       const float* __restrict__ root,
                                                       const float* __restrict__ bias,
                                                       const float* __restrict__ invdeg,
                                                       float* __restrict__ out)
{
    int idx = blockIdx.x * 256 + threadIdx.x;
    int n = idx / COUT, o = idx % COUT;
    if (n >= Nn) return;
    float r0 = 0.f, r1 = 0.f;
#pragma unroll
    for (int i = 0; i < CIN; i += 2) {
        r0 += xin[n * CIN + i] * root[i * COUT + o];
        if (CIN > 1) r1 += xin[n * CIN + i + 1] * root[(i + 1) * COUT + o];
    }
    float v = agg[n * COUT + o] * invdeg[n] + r0 + r1 + bias[o];
    out[n * COUT + o] = v > 0.f ? v : expm1f(v);
}

// ---------------------------------------------------------------- lin1: 64 -> 256, elu, emit f16
__global__ __launch_bounds__(256) void lin1_kernel(const float* __restrict__ h,
                                                   const float* __restrict__ w1,
                                                   const float* __restrict__ b1,
                                                   _Float16* __restrict__ out)
{
    int n = blockIdx.x;
    __shared__ float hl[64];
    if (threadIdx.x < 64) hl[threadIdx.x] = h[n * 64 + threadIdx.x];
    __syncthreads();
    int j = threadIdx.x;
    float a0 = b1[j], a1 = 0.f, a2 = 0.f, a3 = 0.f;
#pragma unroll
    for (int i = 0; i < 64; i += 4) {
        a0 += hl[i + 0] * w1[(i + 0) * 256 + j];
        a1 += hl[i + 1] * w1[(i + 1) * 256 + j];
        a2 += hl[i + 2] * w1[(i + 2) * 256 + j];
        a3 += hl[i + 3] * w1[(i + 3) * 256 + j];
    }
    float acc = (a0 + a1) + (a2 + a3);
    float v = acc > 0.f ? acc : expm1f(acc);
    out[(size_t)n * 256 + j] = (_Float16)v;
}

// ---------------------------------------------------------------- w2 transpose + f16 convert
__global__ __launch_bounds__(256) void w2t_kernel(const float* __restrict__ w2,
                                                  _Float16* __restrict__ w2t)
{
    __shared__ float t[32][33];
    int n0 = blockIdx.x * 32;       // class dim tile
    int k0 = blockIdx.y * 32;       // feature dim tile
    int tx = threadIdx.x & 31, ty = threadIdx.x >> 5;   // ty: 0..7
#pragma unroll
    for (int q = 0; q < 4; ++q) {
        int k = k0 + ty + 8 * q, n = n0 + tx;
        t[ty + 8 * q][tx] = (n < NCLS) ? w2[(size_t)k * NCLS + n] : 0.f;
    }
    __syncthreads();
#pragma unroll
    for (int q = 0; q < 4; ++q) {
        int n = n0 + ty + 8 * q;
        w2t[(size_t)n * 256 + k0 + tx] = (_Float16)t[tx][ty + 8 * q];
    }
}

// ---------------------------------------------------------------- lin2 via MFMA (f16)
__global__ __launch_bounds__(256) void lin2_mfma_kernel(const _Float16* __restrict__ hf,
                                                        const _Float16* __restrict__ w2t,
                                                        const float* __restrict__ b2,
                                                        float* __restrict__ out)
{
    const int tid  = threadIdx.x;
    const int lane = tid & 63, wid = tid >> 6;
    const int wr = wid & 1, wc = wid >> 1;
    const int quad = lane >> 4, lq = lane & 15;

    const int mbase = blockIdx.x * 64 + wr * 32;
    const int nbase = blockIdx.y * 128 + wc * 64;

    f32x4 acc[2][4];
#pragma unroll
    for (int i = 0; i < 2; ++i)
#pragma unroll
        for (int j = 0; j < 4; ++j) acc[i][j] = (f32x4){0.f, 0.f, 0.f, 0.f};

    for (int kc = 0; kc < 256; kc += 32) {
        f16x8 af[2], bfr[4];
#pragma unroll
        for (int mt = 0; mt < 2; ++mt)
            af[mt] = *(const f16x8*)(hf + (size_t)(mbase + mt * 16 + lq) * 256 + kc + quad * 8);
#pragma unroll
        for (int nt = 0; nt < 4; ++nt)
            bfr[nt] = *(const f16x8*)(w2t + (size_t)(nbase + nt * 16 + lq) * 256 + kc + quad * 8);
#pragma unroll
        for (int mt = 0; mt < 2; ++mt)
#pragma unroll
            for (int nt = 0; nt < 4; ++nt)
                acc[mt][nt] = __builtin_amdgcn_mfma_f32_16x16x32_f16(af[mt], bfr[nt], acc[mt][nt], 0, 0, 0);
    }

#pragma unroll
    for (int nt = 0; nt < 4; ++nt) {
        int col = nbase + nt * 16 + lq;
        if (col >= NCLS) continue;
        float bb = b2[col];
#pragma unroll
        for (int mt = 0; mt < 2; ++mt) {
#pragma unroll
            for (int r = 0; r < 4; ++r) {
                int row = mbase + mt * 16 + quad * 4 + r;
                if (row < Nn) out[(size_t)row * NCLS + col] = acc[mt][nt][r] + bb;
            }
        }
    }
}

// ---------------------------------------------------------------- log_softmax (in place)
__global__ __launch_bounds__(1024) void lsm_kernel(float* __restrict__ out)
{
    int row = blockIdx.x;
    float* p = out + (size_t)row * NCLS;
    __shared__ float red[16];
    int tid = threadIdx.x, lane = tid & 63, wid = tid >> 6;

    float m = -3.4e38f;
    for (int jj = tid; jj < NCLS; jj += 1024) m = fmaxf(m, p[jj]);
#pragma unroll
    for (int off = 32; off > 0; off >>= 1) m = fmaxf(m, __shfl_down(m, off));
    if (lane == 0) red[wid] = m;
    __syncthreads();
    if (tid == 0) {
        float mm = red[0];
        for (int w = 1; w < 16; ++w) mm = fmaxf(mm, red[w]);
        red[0] = mm;
    }
    __syncthreads();
    m = red[0];
    __syncthreads();

    float s = 0.f;
    for (int jj = tid; jj < NCLS; jj += 1024) s += expf(p[jj] - m);
#pragma unroll
    for (int off = 32; off > 0; off >>= 1) s += __shfl_down(s, off);
    if (lane == 0) red[wid] = s;
    __syncthreads();
    if (tid == 0) {
        float ss = 0.f;
        for (int w = 1; w < 16; ++w) ss += red[w];
        red[0] += ss;
    }
    __syncthreads();
    float lse = m + logf(red[0]);
    for (int jj = tid; jj < NCLS; jj += 1024) p[jj] -= lse;
}

// ---------------------------------------------------------------- launch
extern "C" void kernel_launch(void* const* d_in, const int* in_sizes, int n_in,
                              void* d_out, int out_size, void* d_ws, size_t ws_size,
                              hipStream_t stream)
{
    const float* x      = (const float*)d_in[0];
    const int*   ei     = (const int*)d_in[1];
    const float* pseudo = (const float*)d_in[2];
    const float* W1     = (const float*)d_in[3];
    const float* root1  = (const float*)d_in[4];
    const float* b1     = (const float*)d_in[5];
    const float* W2     = (const float*)d_in[6];
    const float* root2  = (const float*)d_in[7];
    const float* b2     = (const float*)d_in[8];
    const float* Ws     = (const float*)d_in[9];
    const float* roots  = (const float*)d_in[10];
    const float* bs     = (const float*)d_in[11];
    const float* l1w    = (const float*)d_in[12];
    const float* l1b    = (const float*)d_in[13];
    const float* l2w    = (const float*)d_in[14];
    const float* l2b    = (const float*)d_in[15];
    float* out = (float*)d_out;

    const int* srcA = ei;
    const int* dstA = ei + Ee;

    char* base = (char*)d_ws;
    size_t off = 0;
    auto carve = [&](size_t bytes) -> void* {
        void* p = base + off;
        off += (bytes + 255) & ~(size_t)255;
        return p;
    };
    float* bw     = (float*)carve((size_t)Ee * 8 * 4);
    int*   fl     = (int*)carve((size_t)Ee * 8 * 4);
    int*   hist   = (int*)carve((size_t)NBUCK * 4);
    int*   boff   = (int*)carve((size_t)(NBUCK + 1) * 4);
    int*   cursor = (int*)carve((size_t)NBUCK * 4);
    uint2* recs   = (uint2*)carve((size_t)Ee * 8 * 8);
    int*   degi   = (int*)carve((size_t)Nn * 4);
    float* invdeg = (float*)carve((size_t)Nn * 4);
    float* agg    = (float*)carve((size_t)Nn * 64 * 4);
    float* hA     = (float*)carve((size_t)Nn * 64 * 4);
    float* hB     = (float*)carve((size_t)Nn * 64 * 4);
    _Float16* hf  = (_Float16*)carve((size_t)MPAD * 256 * 2);
    _Float16* w2t = (_Float16*)carve((size_t)NPAD * 256 * 2);
    _Float16* wb2 = (_Float16*)carve((size_t)NKER * 4 * 1 * 512 * 2);       // 512 KB
    _Float16* wbs = (_Float16*)carve((size_t)4 * NKER * 4 * 2 * 512 * 2);   // 4 MB
    (void)ws_size; (void)n_in; (void)in_sizes; (void)out_size;

    hipMemsetAsync(hist, 0, (size_t)NBUCK * 4, stream);
    hipMemsetAsync(degi, 0, (size_t)Nn * 4, stream);
    hipMemsetAsync(hf, 0, (size_t)MPAD * 256 * 2, stream);    // zero-pad rows >= Nn

    basis_kernel<<<(Ee + 255) / 256, 256, 0, stream>>>(pseudo, bw, fl);
    deg_kernel<<<(Ee + 255) / 256, 256, 0, stream>>>(dstA, degi);
    invdeg_kernel<<<(Nn + 255) / 256, 256, 0, stream>>>(degi, invdeg);
    hist_kernel<<<(Ee * 8 + 255) / 256, 256, 0, stream>>>(dstA, fl, hist);
    scan_kernel<<<1, 1024, 0, stream>>>(hist, boff);
    hipMemcpyAsync(cursor, boff, (size_t)NBUCK * 4, hipMemcpyDeviceToDevice, stream);
    fill_kernel<<<(Ee * 8 + 255) / 256, 256, 0, stream>>>(srcA, dstA, bw, fl, cursor, recs);
    w2t_kernel<<<dim3((NPAD + 31) / 32, 8), 256, 0, stream>>>(l2w, w2t);

    // W pre-transpose to f16 MFMA fragment blobs
    wb_kernel<32><<<(NKER * 4 * 1 * 512 + 255) / 256, 256, 0, stream>>>(W2, wb2);
    for (int l = 0; l < 4; ++l)
        wb_kernel<64><<<(NKER * 4 * 2 * 512 + 255) / 256, 256, 0, stream>>>(
            Ws + (size_t)l * NKER * 64 * 64, wbs + (size_t)l * NKER * 4 * 2 * 512);

    const dim3 cgrid(NBLK, KS);

    // layer 1: 1 -> 32
    hipMemsetAsync(agg, 0, (size_t)Nn * 64 * 4, stream);
    conv1_kernel<<<cgrid, 256, 0, stream>>>(recs, boff, x, W1, agg);
    epilogue_kernel<1, 32><<<(Nn * 32 + 255) / 256, 256, 0, stream>>>(agg, x, root1, b1, invdeg, hA);

    // layer 2: 32 -> 64
    hipMemsetAsync(agg, 0, (size_t)Nn * 64 * 4, stream);
    conv_mfma_kernel<32><<<cgrid, 256, 0, stream>>>(recs, boff, hA, wb2, agg);
    epilogue_kernel<32, 64><<<(Nn * 64 + 255) / 256, 256, 0, stream>>>(agg, hA, root2, b2, invdeg, hB);

    // layers 3..6: 64 -> 64
    float* cin = hB;
    float* cot = hA;
    for (int l = 0; l < 4; ++l) {
        hipMemsetAsync(agg, 0, (size_t)Nn * 64 * 4, stream);
        conv_mfma_kernel<64><<<cgrid, 256, 0, stream>>>(recs, boff, cin,
                                                        wbs + (size_t)l * NKER * 4 * 2 * 512, agg);
        epilogue_kernel<64, 64><<<(Nn * 64 + 255) / 256, 256, 0, stream>>>(
            agg, cin, roots + (size_t)l * 64 * 64, bs + (size_t)l * 64, invdeg, cot);
        float* t = cin; cin = cot; cot = t;
    }

    lin1_kernel<<<Nn, 256, 0, stream>>>(cin, l1w, l1b, hf);
    lin2_mfma_kernel<<<dim3(MPAD / 64, NPAD / 128), 256, 0, stream>>>(hf, w2t, l2b, out);
    lsm_kernel<<<Nn, 1024, 0, stream>>>(out);
}

// Round 6
// 3971.368 us; speedup vs baseline: 1.3545x; 1.0406x over previous
//
#include <hip/hip_runtime.h>
#include <hip/hip_bf16.h>
#include <hip/hip_fp16.h>
#include <math.h>

#define Nn 10000
#define Ee 160000
#define NPB 64            // dst nodes per block
#define NBLK 157          // 157 * 64 = 10048 >= 10000
#define NKER 125
#define NBUCK (NBLK * NKER)
#define KCHUNK 8          // k-range per grid.y slice (16 slices)
#define KS ((NKER + KCHUNK - 1) / KCHUNK)

#define MPAD 10048        // 157 * 64
#define NPAD 6912         // 54 * 128
#define NCLS 6890

typedef float    f32x4 __attribute__((ext_vector_type(4)));
typedef _Float16 f16x8 __attribute__((ext_vector_type(8)));

// ---------------------------------------------------------------- basis
__global__ __launch_bounds__(256) void basis_kernel(const float* __restrict__ pseudo,
                                                    float* __restrict__ bw,
                                                    int* __restrict__ fl)
{
    int e = blockIdx.x * 256 + threadIdx.x;
    if (e >= Ee) return;
    float p0 = pseudo[e * 3 + 0] * 4.f;
    float p1 = pseudo[e * 3 + 1] * 4.f;
    float p2 = pseudo[e * 3 + 2] * 4.f;
    float f0 = floorf(p0), f1 = floorf(p1), f2 = floorf(p2);
    float fr0 = p0 - f0, fr1 = p1 - f1, fr2 = p2 - f2;
    int lo0 = (int)f0; lo0 = lo0 < 0 ? 0 : (lo0 > 4 ? 4 : lo0);
    int lo1 = (int)f1; lo1 = lo1 < 0 ? 0 : (lo1 > 4 ? 4 : lo1);
    int lo2 = (int)f2; lo2 = lo2 < 0 ? 0 : (lo2 > 4 ? 4 : lo2);
    int hi0 = lo0 + 1 > 4 ? 4 : lo0 + 1;
    int hi1 = lo1 + 1 > 4 ? 4 : lo1 + 1;
    int hi2 = lo2 + 1 > 4 ? 4 : lo2 + 1;
#pragma unroll
    for (int s = 0; s < 8; ++s) {
        int c0 = (s >> 2) & 1, c1 = (s >> 1) & 1, c2 = s & 1;
        float b = (c0 ? fr0 : 1.f - fr0) * (c1 ? fr1 : 1.f - fr1) * (c2 ? fr2 : 1.f - fr2);
        int f = (c0 ? hi0 : lo0) + 5 * (c1 ? hi1 : lo1) + 25 * (c2 ? hi2 : lo2);
        bw[e * 8 + s] = b;
        fl[e * 8 + s] = f;
    }
}

// ---------------------------------------------------------------- degree
__global__ __launch_bounds__(256) void deg_kernel(const int* __restrict__ dst, int* __restrict__ degi)
{
    int e = blockIdx.x * 256 + threadIdx.x;
    if (e >= Ee) return;
    atomicAdd(&degi[dst[e]], 1);
}

__global__ __launch_bounds__(256) void invdeg_kernel(const int* __restrict__ degi, float* __restrict__ invdeg)
{
    int n = blockIdx.x * 256 + threadIdx.x;
    if (n >= Nn) return;
    int d = degi[n];
    invdeg[n] = 1.f / (float)(d > 0 ? d : 1);
}

// ---------------------------------------------------------------- pair sort (counting sort by (dstblock, k))
__global__ __launch_bounds__(256) void hist_kernel(const int* __restrict__ dst, const int* __restrict__ fl,
                                                   int* __restrict__ hist)
{
    int t = blockIdx.x * 256 + threadIdx.x;
    if (t >= Ee * 8) return;
    int e = t >> 3;
    int key = (dst[e] >> 6) * NKER + fl[t];
    atomicAdd(&hist[key], 1);
}

__global__ __launch_bounds__(1024) void scan_kernel(const int* __restrict__ hist, int* __restrict__ boff)
{
    const int T = 1024;
    const int per = (NBUCK + T - 1) / T;
    int t = threadIdx.x;
    int beg = t * per;
    int end = beg + per; if (end > NBUCK) end = NBUCK;
    int s = 0;
    for (int i = beg; i < end && i < NBUCK; ++i) s += hist[i];
    __shared__ int tmp[1024];
    tmp[t] = s;
    __syncthreads();
    for (int o2 = 1; o2 < 1024; o2 <<= 1) {
        int v = (t >= o2) ? tmp[t - o2] : 0;
        __syncthreads();
        tmp[t] += v;
        __syncthreads();
    }
    int run = tmp[t] - s;   // exclusive prefix for this thread's range
    for (int i = beg; i < end && i < NBUCK; ++i) { boff[i] = run; run += hist[i]; }
    if (t == T - 1) boff[NBUCK] = run;
}

__global__ __launch_bounds__(256) void fill_kernel(const int* __restrict__ srcA, const int* __restrict__ dstA,
                                                   const float* __restrict__ bw, const int* __restrict__ fl,
                                                   int* __restrict__ cursor, uint2* __restrict__ recs)
{
    int t = blockIdx.x * 256 + threadIdx.x;
    if (t >= Ee * 8) return;
    int e = t >> 3;
    int d = dstA[e];
    int key = (d >> 6) * NKER + fl[t];
    int pos = atomicAdd(&cursor[key], 1);
    unsigned meta = (unsigned)srcA[e] | ((unsigned)(d & 63) << 16);
    recs[pos] = make_uint2(meta, __float_as_uint(bw[t]));
}

// ---------------------------------------------------------------- W pre-transpose to f16 MFMA B-fragment layout
// WB[k][nt][kc][lane][8]: lane (lq=col,quad) holds W[kc*32+quad*8+j][nt*16+lq]
template <int CIN>
__global__ __launch_bounds__(256) void wb_kernel(const float* __restrict__ W, _Float16* __restrict__ WB)
{
    constexpr int NKC = CIN / 32;
    int t = blockIdx.x * 256 + threadIdx.x;
    int total = NKER * 4 * NKC * 512;
    if (t >= total) return;
    int j = t & 7;
    int lane = (t >> 3) & 63;
    int rem = t >> 9;
    int kc = rem % NKC; rem /= NKC;
    int nt = rem & 3; rem >>= 2;
    int k = rem;
    int ki = kc * 32 + (lane >> 4) * 8 + j;
    int o  = nt * 16 + (lane & 15);
    WB[t] = (_Float16)W[((size_t)k * CIN + ki) * 64 + o];
}

// ---------------------------------------------------------------- spline conv via MFMA (CIN in {32,64}, COUT=64)
// Wave = bucket (dstblock, k). R5 was ~97% stalled (VALU 1.9%, MFMA 0.8%):
// per-batch recs->gather dependent VMEM chain + 64-line gathers + LDS
// staging round-trip, at 2.75 waves/SIMD. Fixes here:
//  - x stored f16: gathers land DIRECTLY in A-fragment layout (lane(lq,quad)
//    reads 16B of row src(lq)), 16 cachelines/instr, no LDS staging/cvt.
//  - bucket records pre-staged to LDS in one coalesced burst: per-batch
//    metadata is an LDS read, only VMEM per batch is the 1-2 A-gathers.
//  - wt applied post-MFMA (linearity), so padded slots are wt=0.
//  - LDS 25KB + low VGPR + KCHUNK=8 -> ~20 waves/CU for latency hiding.
template <int CIN>
__global__ __launch_bounds__(256, 5) void conv_mfma_kernel(const uint2* __restrict__ recs,
                                                           const int* __restrict__ boff,
                                                           const _Float16* __restrict__ xin,
                                                           const _Float16* __restrict__ WB,
                                                           float* __restrict__ agg)
{
    constexpr int NKC = CIN / 32;          // K chunks of 32
    constexpr int STR = 65;                // aggl row stride (floats)

    __shared__ float aggl[NPB * STR];
    __shared__ uint2 rbuf[4][256];

    const int blk = blockIdx.x;
    for (int idx = threadIdx.x; idx < NPB * STR; idx += 256) aggl[idx] = 0.f;
    __syncthreads();

    const int lane = threadIdx.x & 63;
    const int wid  = threadIdx.x >> 6;
    const int lq   = lane & 15;
    const int quad = lane >> 4;

    int k0 = blockIdx.y * KCHUNK;
    int k1 = k0 + KCHUNK; if (k1 > NKER) k1 = NKER;

    for (int k = k0 + wid; k < k1; k += 4) {
        const int kk = __builtin_amdgcn_readfirstlane(k);
        const int bidx = blk * NKER + kk;
        const int pb = boff[bidx], pe = boff[bidx + 1];
        if (pb >= pe) continue;

        // B fragments for W[kk], once per bucket (16B/lane coalesced loads)
        f16x8 bfr[4][NKC];
        {
            const _Float16* __restrict__ wbk = WB + (size_t)kk * (4 * NKC * 512);
#pragma unroll
            for (int nt = 0; nt < 4; ++nt)
#pragma unroll
                for (int kc = 0; kc < NKC; ++kc)
                    bfr[nt][kc] = *(const f16x8*)(wbk + (size_t)((nt * NKC + kc) * 64 + lane) * 8);
        }

        for (int ps = pb; ps < pe; ps += 256) {
            const int cn = (pe - ps < 256) ? (pe - ps) : 256;
            // stage this chunk's records into LDS (coalesced, all loads in flight at once)
#pragma unroll
            for (int i = 0; i < 4; ++i) {
                int idx = i * 64 + lane;
                int rid = ps + idx;
                rbuf[wid][idx] = recs[rid < pe ? rid : pe - 1];
            }
            const int nb = (cn + 15) >> 4;
            for (int b = 0; b < nb; ++b) {
                const int rbase = b * 16;
                // A-fragment gather: lane(lq,quad) reads 16B of row src(lq)
                uint2 rme = rbuf[wid][rbase + lq];
                int src = (int)(rme.x & 0xFFFFu);
                f16x8 a[NKC];
#pragma unroll
                for (int kc = 0; kc < NKC; ++kc)
                    a[kc] = *(const f16x8*)(xin + (size_t)src * CIN + kc * 32 + quad * 8);

                // metadata for my 4 accumulator rows (records rbase+quad*4+r)
                uint2 rw[4];
#pragma unroll
                for (int r = 0; r < 4; ++r) rw[r] = rbuf[wid][rbase + quad * 4 + r];

                f32x4 acc[4];
#pragma unroll
                for (int nt = 0; nt < 4; ++nt) {
                    acc[nt] = (f32x4){0.f, 0.f, 0.f, 0.f};
#pragma unroll
                    for (int kc = 0; kc < NKC; ++kc)
                        acc[nt] = __builtin_amdgcn_mfma_f32_16x16x32_f16(a[kc], bfr[nt][kc], acc[nt], 0, 0, 0);
                }

#pragma unroll
                for (int r = 0; r < 4; ++r) {
                    float wt = (rbase + quad * 4 + r < cn) ? __uint_as_float(rw[r].y) : 0.f;
                    int db = (int)(rw[r].x >> 16) * STR;
#pragma unroll
                    for (int nt = 0; nt < 4; ++nt)
                        atomicAdd(&aggl[db + nt * 16 + lq], wt * acc[nt][r]);
                }
            }
        }
    }
    __syncthreads();
    for (int idx = threadIdx.x; idx < NPB * 64; idx += 256) {
        int n = blk * NPB + (idx >> 6);
        if (n < Nn) atomicAdd(&agg[n * 64 + (idx & 63)], aggl[(idx >> 6) * STR + (idx & 63)]);
    }
}

// ---------------------------------------------------------------- layer-1 conv (CIN=1, COUT=32): lane = record
__global__ __launch_bounds__(256, 3) void conv1_kernel(const uint2* __restrict__ recs,
                                                       const int* __restrict__ boff,
                                                       const float* __restrict__ xin,
                                                       const float* __restrict__ W,
                                                       float* __restrict__ agg)
{
    constexpr int STR = 33;
    __shared__ float aggl[NPB * STR];
    const int blk = blockIdx.x;
    for (int idx = threadIdx.x; idx < NPB * STR; idx += 256) aggl[idx] = 0.f;
    __syncthreads();

    const int lane = threadIdx.x & 63;
    const int wid  = threadIdx.x >> 6;
    int k0 = blockIdx.y * KCHUNK;
    int k1 = k0 + KCHUNK; if (k1 > NKER) k1 = NKER;

    for (int k = k0 + wid; k < k1; k += 4) {
        const int kk = __builtin_amdgcn_readfirstlane(k);
        const int bidx = blk * NKER + kk;
        const int pb = boff[bidx], pe = boff[bidx + 1];
        if (pb >= pe) continue;
        const float* __restrict__ Wk = W + kk * 32;
        float w[32];
#pragma unroll
        for (int o = 0; o < 32; ++o) w[o] = Wk[o];   // wave-uniform -> SGPRs, once per bucket

        for (int p = pb; p < pe; p += 64) {
            int j = p + lane;
            bool v = j < pe;
            uint2 rr = recs[v ? j : (pe - 1)];
            float wt = v ? __uint_as_float(rr.y) : 0.f;
            float xv = xin[rr.x & 0xFFFFu] * wt;
            int dbase = (int)(rr.x >> 16) * STR;
#pragma unroll
            for (int o = 0; o < 32; ++o)
                atomicAdd(&aggl[dbase + o], xv * w[o]);
        }
    }
    __syncthreads();
    for (int idx = threadIdx.x; idx < NPB * 32; idx += 256) {
        int n = blk * NPB + (idx >> 5);
        if (n < Nn) atomicAdd(&agg[n * 32 + (idx & 31)], aggl[(idx >> 5) * STR + (idx & 31)]);
    }
}

// ---------------------------------------------------------------- conv epilogue: /deg + root + bias + elu
// writes f32 (for next root-term / lin1) AND f16 (for next conv's A-gather)
template <int CIN, int COUT>
__global__ __launch_bounds__(256) void epilogue_kernel(const float* __restrict__ agg,
                                                       const float* __restrict__ xin,
                                                       const float* __restrict__ root,
                                                       const float* __restrict__ bias,
                                                       const float* __restrict__ invdeg,
                                                       float* __restrict__ out32,
                                                       _Float16* __restrict__ out16)
{
    int idx = blockIdx.x * 256 + threadIdx.x;
    int n = idx / COUT, o = idx % COUT;
    if (n >= Nn) return;
    float r0 = 0.f, r1 = 0.f;
#pragma unroll
    for (int i = 0; i < CIN; i += 2) {
        r0 += xin[n * CIN + i] * root[i * COUT + o];
        if (CIN > 1) r1 += xin[n * CIN + i + 1] * root[(i + 1) * COUT + o];
    }
    float v = agg[n * COUT + o] * invdeg[n] + r0 + r1 + bias[o];
    v = v > 0.f ? v : expm1f(v);
    out32[n * COUT + o] = v;
    out16[n * COUT + o] = (_Float16)v;
}

// ---------------------------------------------------------------- lin1: 64 -> 256, elu, emit f16
__global__ __launch_bounds__(256) void lin1_kernel(const float* __restrict__ h,
                                                   const float* __restrict__ w1,
                                                   const float* __restrict__ b1,
                                                   _Float16* __restrict__ out)
{
    int n = blockIdx.x;
    __shared__ float hl[64];
    if (threadIdx.x < 64) hl[threadIdx.x] = h[n * 64 + threadIdx.x];
    __syncthreads();
    int j = threadIdx.x;
    float a0 = b1[j], a1 = 0.f, a2 = 0.f, a3 = 0.f;
#pragma unroll
    for (int i = 0; i < 64; i += 4) {
        a0 += hl[i + 0] * w1[(i + 0) * 256 + j];
        a1 += hl[i + 1] * w1[(i + 1) * 256 + j];
        a2 += hl[i + 2] * w1[(i + 2) * 256 + j];
        a3 += hl[i + 3] * w1[(i + 3) * 256 + j];
    }
    float acc = (a0 + a1) + (a2 + a3);
    float v = acc > 0.f ? acc : expm1f(acc);
    out[(size_t)n * 256 + j] = (_Float16)v;
}

// ---------------------------------------------------------------- w2 transpose + f16 convert
__global__ __launch_bounds__(256) void w2t_kernel(const float* __restrict__ w2,
                                                  _Float16* __restrict__ w2t)
{
    __shared__ float t[32][33];
    int n0 = blockIdx.x * 32;       // class dim tile
    int k0 = blockIdx.y * 32;       // feature dim tile
    int tx = threadIdx.x & 31, ty = threadIdx.x >> 5;   // ty: 0..7
#pragma unroll
    for (int q = 0; q < 4; ++q) {
        int k = k0 + ty + 8 * q, n = n0 + tx;
        t[ty + 8 * q][tx] = (n < NCLS) ? w2[(size_t)k * NCLS + n] : 0.f;
    }
    __syncthreads();
#pragma unroll
    for (int q = 0; q < 4; ++q) {
        int n = n0 + ty + 8 * q;
        w2t[(size_t)n * 256 + k0 + tx] = (_Float16)t[tx][ty + 8 * q];
    }
}

// ---------------------------------------------------------------- lin2 via MFMA (f16)
__global__ __launch_bounds__(256) void lin2_mfma_kernel(const _Float16* __restrict__ hf,
                                                        const _Float16* __restrict__ w2t,
                                                        const float* __restrict__ b2,
                                                        float* __restrict__ out)
{
    const int tid  = threadIdx.x;
    const int lane = tid & 63, wid = tid >> 6;
    const int wr = wid & 1, wc = wid >> 1;
    const int quad = lane >> 4, lq = lane & 15;

    const int mbase = blockIdx.x * 64 + wr * 32;
    const int nbase = blockIdx.y * 128 + wc * 64;

    f32x4 acc[2][4];
#pragma unroll
    for (int i = 0; i < 2; ++i)
#pragma unroll
        for (int j = 0; j < 4; ++j) acc[i][j] = (f32x4){0.f, 0.f, 0.f, 0.f};

    for (int kc = 0; kc < 256; kc += 32) {
        f16x8 af[2], bfr[4];
#pragma unroll
        for (int mt = 0; mt < 2; ++mt)
            af[mt] = *(const f16x8*)(hf + (size_t)(mbase + mt * 16 + lq) * 256 + kc + quad * 8);
#pragma unroll
        for (int nt = 0; nt < 4; ++nt)
            bfr[nt] = *(const f16x8*)(w2t + (size_t)(nbase + nt * 16 + lq) * 256 + kc + quad * 8);
#pragma unroll
        for (int mt = 0; mt < 2; ++mt)
#pragma unroll
            for (int nt = 0; nt < 4; ++nt)
                acc[mt][nt] = __builtin_amdgcn_mfma_f32_16x16x32_f16(af[mt], bfr[nt], acc[mt][nt], 0, 0, 0);
    }

#pragma unroll
    for (int nt = 0; nt < 4; ++nt) {
        int col = nbase + nt * 16 + lq;
        if (col >= NCLS) continue;
        float bb = b2[col];
#pragma unroll
        for (int mt = 0; mt < 2; ++mt) {
#pragma unroll
            for (int r = 0; r < 4; ++r) {
                int row = mbase + mt * 16 + quad * 4 + r;
                if (row < Nn) out[(size_t)row * NCLS + col] = acc[mt][nt][r] + bb;
            }
        }
    }
}

// ---------------------------------------------------------------- log_softmax (in place)
__global__ __launch_bounds__(1024) void lsm_kernel(float* __restrict__ out)
{
    int row = blockIdx.x;
    float* p = out + (size_t)row * NCLS;
    __shared__ float red[16];
    int tid = threadIdx.x, lane = tid & 63, wid = tid >> 6;

    float m = -3.4e38f;
    for (int jj = tid; jj < NCLS; jj += 1024) m = fmaxf(m, p[jj]);
#pragma unroll
    for (int off = 32; off > 0; off >>= 1) m = fmaxf(m, __shfl_down(m, off));
    if (lane == 0) red[wid] = m;
    __syncthreads();
    if (tid == 0) {
        float mm = red[0];
        for (int w = 1; w < 16; ++w) mm = fmaxf(mm, red[w]);
        red[0] = mm;
    }
    __syncthreads();
    m = red[0];
    __syncthreads();

    float s = 0.f;
    for (int jj = tid; jj < NCLS; jj += 1024) s += expf(p[jj] - m);
#pragma unroll
    for (int off = 32; off > 0; off >>= 1) s += __shfl_down(s, off);
    if (lane == 0) red[wid] = s;
    __syncthreads();
    if (tid == 0) {
        float ss = 0.f;
        for (int w = 1; w < 16; ++w) ss += red[w];
        red[0] += ss;
    }
    __syncthreads();
    float lse = m + logf(red[0]);
    for (int jj = tid; jj < NCLS; jj += 1024) p[jj] -= lse;
}

// ---------------------------------------------------------------- launch
extern "C" void kernel_launch(void* const* d_in, const int* in_sizes, int n_in,
                              void* d_out, int out_size, void* d_ws, size_t ws_size,
                              hipStream_t stream)
{
    const float* x      = (const float*)d_in[0];
    const int*   ei     = (const int*)d_in[1];
    const float* pseudo = (const float*)d_in[2];
    const float* W1     = (const float*)d_in[3];
    const float* root1  = (const float*)d_in[4];
    const float* b1     = (const float*)d_in[5];
    const float* W2     = (const float*)d_in[6];
    const float* root2  = (const float*)d_in[7];
    const float* b2     = (const float*)d_in[8];
    const float* Ws     = (const float*)d_in[9];
    const float* roots  = (const float*)d_in[10];
    const float* bs     = (const float*)d_in[11];
    const float* l1w    = (const float*)d_in[12];
    const float* l1b    = (const float*)d_in[13];
    const float* l2w    = (const float*)d_in[14];
    const float* l2b    = (const float*)d_in[15];
    float* out = (float*)d_out;

    const int* srcA = ei;
    const int* dstA = ei + Ee;

    char* base = (char*)d_ws;
    size_t off = 0;
    auto carve = [&](size_t bytes) -> void* {
        void* p = base + off;
        off += (bytes + 255) & ~(size_t)255;
        return p;
    };
    float* bw     = (float*)carve((size_t)Ee * 8 * 4);
    int*   fl     = (int*)carve((size_t)Ee * 8 * 4);
    int*   hist   = (int*)carve((size_t)NBUCK * 4);
    int*   boff   = (int*)carve((size_t)(NBUCK + 1) * 4);
    int*   cursor = (int*)carve((size_t)NBUCK * 4);
    uint2* recs   = (uint2*)carve((size_t)Ee * 8 * 8);
    int*   degi   = (int*)carve((size_t)Nn * 4);
    float* invdeg = (float*)carve((size_t)Nn * 4);
    float* agg    = (float*)carve((size_t)Nn * 64 * 4);
    float* hA     = (float*)carve((size_t)Nn * 64 * 4);
    float* hB     = (float*)carve((size_t)Nn * 64 * 4);
    _Float16* hA16 = (_Float16*)carve((size_t)Nn * 64 * 2);
    _Float16* hB16 = (_Float16*)carve((size_t)Nn * 64 * 2);
    _Float16* hf  = (_Float16*)carve((size_t)MPAD * 256 * 2);
    _Float16* w2t = (_Float16*)carve((size_t)NPAD * 256 * 2);
    _Float16* wb2 = (_Float16*)carve((size_t)NKER * 4 * 1 * 512 * 2);       // 512 KB
    _Float16* wbs = (_Float16*)carve((size_t)4 * NKER * 4 * 2 * 512 * 2);   // 4 MB
    (void)ws_size; (void)n_in; (void)in_sizes; (void)out_size;

    hipMemsetAsync(hist, 0, (size_t)NBUCK * 4, stream);
    hipMemsetAsync(degi, 0, (size_t)Nn * 4, stream);
    hipMemsetAsync(hf, 0, (size_t)MPAD * 256 * 2, stream);    // zero-pad rows >= Nn

    basis_kernel<<<(Ee + 255) / 256, 256, 0, stream>>>(pseudo, bw, fl);
    deg_kernel<<<(Ee + 255) / 256, 256, 0, stream>>>(dstA, degi);
    invdeg_kernel<<<(Nn + 255) / 256, 256, 0, stream>>>(degi, invdeg);
    hist_kernel<<<(Ee * 8 + 255) / 256, 256, 0, stream>>>(dstA, fl, hist);
    scan_kernel<<<1, 1024, 0, stream>>>(hist, boff);
    hipMemcpyAsync(cursor, boff, (size_t)NBUCK * 4, hipMemcpyDeviceToDevice, stream);
    fill_kernel<<<(Ee * 8 + 255) / 256, 256, 0, stream>>>(srcA, dstA, bw, fl, cursor, recs);
    w2t_kernel<<<dim3((NPAD + 31) / 32, 8), 256, 0, stream>>>(l2w, w2t);

    // W pre-transpose to f16 MFMA fragment blobs
    wb_kernel<32><<<(NKER * 4 * 1 * 512 + 255) / 256, 256, 0, stream>>>(W2, wb2);
    for (int l = 0; l < 4; ++l)
        wb_kernel<64><<<(NKER * 4 * 2 * 512 + 255) / 256, 256, 0, stream>>>(
            Ws + (size_t)l * NKER * 64 * 64, wbs + (size_t)l * NKER * 4 * 2 * 512);

    const dim3 cgrid(NBLK, KS);

    // layer 1: 1 -> 32
    hipMemsetAsync(agg, 0, (size_t)Nn * 64 * 4, stream);
    conv1_kernel<<<cgrid, 256, 0, stream>>>(recs, boff, x, W1, agg);
    epilogue_kernel<1, 32><<<(Nn * 32 + 255) / 256, 256, 0, stream>>>(agg, x, root1, b1, invdeg, hA, hA16);

    // layer 2: 32 -> 64
    hipMemsetAsync(agg, 0, (size_t)Nn * 64 * 4, stream);
    conv_mfma_kernel<32><<<cgrid, 256, 0, stream>>>(recs, boff, hA16, wb2, agg);
    epilogue_kernel<32, 64><<<(Nn * 64 + 255) / 256, 256, 0, stream>>>(agg, hA, root2, b2, invdeg, hB, hB16);

    // layers 3..6: 64 -> 64
    float* cin = hB;       float* cot = hA;
    _Float16* cin16 = hB16; _Float16* cot16 = hA16;
    for (int l = 0; l < 4; ++l) {
        hipMemsetAsync(agg, 0, (size_t)Nn * 64 * 4, stream);
        conv_mfma_kernel<64><<<cgrid, 256, 0, stream>>>(recs, boff, cin16,
                                                        wbs + (size_t)l * NKER * 4 * 2 * 512, agg);
        epilogue_kernel<64, 64><<<(Nn * 64 + 255) / 256, 256, 0, stream>>>(
            agg, cin, roots + (size_t)l * 64 * 64, bs + (size_t)l * 64, invdeg, cot, cot16);
        float* t = cin; cin = cot; cot = t;
        _Float16* t16 = cin16; cin16 = cot16; cot16 = t16;
    }

    lin1_kernel<<<Nn, 256, 0, stream>>>(cin, l1w, l1b, hf);
    lin2_mfma_kernel<<<dim3(MPAD / 64, NPAD / 128), 256, 0, stream>>>(hf, w2t, l2b, out);
    lsm_kernel<<<Nn, 1024, 0, stream>>>(out);
}